// Round 12
// baseline (670.886 us; speedup 1.0000x reference)
//
#include <hip/hip_runtime.h>
#include <math.h>

typedef __bf16 bf16_t;
typedef bf16_t bf16x8 __attribute__((ext_vector_type(8)));
typedef bf16_t bf16x4 __attribute__((ext_vector_type(4)));
typedef float  f32x4  __attribute__((ext_vector_type(4)));

#define T_TOK 8192
#define DM 1024
#define DF 4096
#define NE 8
#define NP 16384  // total token-expert pairs = T_TOK * 2

__device__ __forceinline__ f32x4 mfma_bf16(bf16x8 a, bf16x8 b, f32x4 c) {
  return __builtin_amdgcn_mfma_f32_16x16x32_bf16(a, b, c, 0, 0, 0);
}

__device__ __forceinline__ void gload16(const void* g, void* l) {
  __builtin_amdgcn_global_load_lds((const __attribute__((address_space(1))) void*)g,
                                   (__attribute__((address_space(3))) void*)l, 16, 0, 0);
}

// Abramowitz-Stegun 7.1.26 erf, |err| <= 1.5e-7
__device__ __forceinline__ float erf_fast(float x) {
  float ax = fabsf(x);
  float t = 1.f / (1.f + 0.3275911f * ax);
  float p = t * (0.254829592f + t * (-0.284496736f + t * (1.421413741f +
            t * (-1.453152027f + t * 1.061405429f))));
  float r = 1.f - p * __expf(-ax * ax);
  return copysignf(r, x);
}

// Line-pair LDS swizzle within a [256 rows][32 k] bf16 subtile (64B rows).
// byte(row,ch) = (row>>1)*128 + ((((row&1)<<2)|ch) ^ ((row>>1)&7))*16  [R7: 0 conflicts]
__device__ __forceinline__ unsigned swz_off(int row, int ch) {
  return (unsigned)(((row >> 1) << 7) + (((((row & 1) << 2) | ch) ^ ((row >> 1) & 7)) << 4));
}

// meta layout (ints): [0..7]=cnt1 [8..15]=cnt2 [16..23]=cursor [24..31]=off
// [32..39]=probsum(float) [40]=zsum(float)

// ============================ router ============================
__global__ __launch_bounds__(256) void k_router(
    const float* __restrict__ x, const float* __restrict__ gate_w,
    const float* __restrict__ ln_g, const float* __restrict__ ln_b,
    float* __restrict__ out, bf16_t* __restrict__ xn,
    int* __restrict__ eidx, float* __restrict__ gts, int* __restrict__ meta)
{
  int* cnt1 = meta;
  int* cnt2 = meta + 8;
  float* probsum = (float*)(meta + 32);
  float* zsum    = (float*)(meta + 40);

  __shared__ float sprob[8];
  __shared__ float sz;
  __shared__ int sc1[8], sc2[8];
  if (threadIdx.x < 8) { sprob[threadIdx.x] = 0.f; sc1[threadIdx.x] = 0; sc2[threadIdx.x] = 0; }
  if (threadIdx.x == 8) sz = 0.f;
  __syncthreads();

  int lane = threadIdx.x & 63, wv = threadIdx.x >> 6;
  int t = blockIdx.x * 4 + wv;
  const float* xt = x + (size_t)t * DM;

  float4 v[4];
  float s1 = 0.f, s2 = 0.f;
  #pragma unroll
  for (int c = 0; c < 4; ++c) {
    v[c] = *(const float4*)(xt + c * 256 + lane * 4);
    s1 += v[c].x + v[c].y + v[c].z + v[c].w;
    s2 += v[c].x * v[c].x + v[c].y * v[c].y + v[c].z * v[c].z + v[c].w * v[c].w;
  }
  #pragma unroll
  for (int o = 32; o > 0; o >>= 1) { s1 += __shfl_xor(s1, o, 64); s2 += __shfl_xor(s2, o, 64); }
  float mu = s1 * (1.f / DM);
  float var = s2 * (1.f / DM) - mu * mu;
  float rstd = rsqrtf(var + 1e-5f);

  float xv[16];
  #pragma unroll
  for (int c = 0; c < 4; ++c) {
    int d = c * 256 + lane * 4;
    float4 g4 = *(const float4*)(ln_g + d);
    float4 b4 = *(const float4*)(ln_b + d);
    xv[c*4+0] = (v[c].x - mu) * rstd * g4.x + b4.x;
    xv[c*4+1] = (v[c].y - mu) * rstd * g4.y + b4.y;
    xv[c*4+2] = (v[c].z - mu) * rstd * g4.z + b4.z;
    xv[c*4+3] = (v[c].w - mu) * rstd * g4.w + b4.w;
    *(float4*)(out + (size_t)t * DM + d) = v[c];  // residual init
    bf16x4 pk = { (bf16_t)xv[c*4+0], (bf16_t)xv[c*4+1], (bf16_t)xv[c*4+2], (bf16_t)xv[c*4+3] };
    *(bf16x4*)(xn + (size_t)t * DM + d) = pk;
  }

  float lg[8];
  #pragma unroll
  for (int e = 0; e < 8; ++e) {
    float p = 0.f;
    #pragma unroll
    for (int c = 0; c < 4; ++c) {
      int d = c * 256 + lane * 4;
      float4 g4 = *(const float4*)(gate_w + e * DM + d);
      p += xv[c*4+0] * g4.x + xv[c*4+1] * g4.y + xv[c*4+2] * g4.z + xv[c*4+3] * g4.w;
    }
    #pragma unroll
    for (int o = 32; o > 0; o >>= 1) p += __shfl_xor(p, o, 64);
    lg[e] = p;
  }

  if (lane == 0) {
    float m = -1e30f;
    #pragma unroll
    for (int e = 0; e < 8; ++e) { lg[e] = fminf(fmaxf(lg[e], -10.f), 10.f); m = fmaxf(m, lg[e]); }
    float pr[8]; float se = 0.f;
    #pragma unroll
    for (int e = 0; e < 8; ++e) { pr[e] = expf(lg[e] - m); se += pr[e]; }
    float inv = 1.f / se;
    #pragma unroll
    for (int e = 0; e < 8; ++e) pr[e] *= inv;
    float lse = m + logf(se);

    int e0 = 0; float p0 = pr[0];
    #pragma unroll
    for (int e = 1; e < 8; ++e) if (pr[e] > p0) { p0 = pr[e]; e0 = e; }
    int e1 = -1; float p1 = -1.f;
    #pragma unroll
    for (int e = 0; e < 8; ++e) if (e != e0 && pr[e] > p1) { p1 = pr[e]; e1 = e; }
    float s = p0 + p1 + 1e-8f;
    eidx[t*2]   = e0; eidx[t*2+1] = e1;
    gts[t*2]    = p0 / s; gts[t*2+1] = p1 / s;

    atomicAdd(&sc1[e0], 1);
    atomicAdd(&sc2[e0], 1);
    atomicAdd(&sc2[e1], 1);
    #pragma unroll
    for (int e = 0; e < 8; ++e) atomicAdd(&sprob[e], pr[e]);
    atomicAdd(&sz, lse * lse);
  }
  __syncthreads();
  if (threadIdx.x < 8) {
    if (sc1[threadIdx.x]) atomicAdd(&cnt1[threadIdx.x], sc1[threadIdx.x]);
    if (sc2[threadIdx.x]) atomicAdd(&cnt2[threadIdx.x], sc2[threadIdx.x]);
    atomicAdd(&probsum[threadIdx.x], sprob[threadIdx.x]);
  }
  if (threadIdx.x == 8) atomicAdd(zsum, sz);
}

// ========== merged weight convert+transpose (w1 and w2 in one grid) ==========
__global__ __launch_bounds__(256) void k_convT2(
    const float* __restrict__ w1, bf16_t* __restrict__ w1t,
    const float* __restrict__ w2, bf16_t* __restrict__ w2t)
{
  int bid = blockIdx.x;
  const float* s; bf16_t* d; int R, C, c0, r0;
  if (bid < 8192) {
    int e = bid >> 10, rem = bid & 1023;
    R = DM; C = DF;
    s = w1 + (size_t)e * R * C; d = w1t + (size_t)e * R * C;
    c0 = (rem & 63) * 64; r0 = (rem >> 6) * 64;
  } else {
    int e = (bid - 8192) >> 10, rem = (bid - 8192) & 1023;
    R = DF; C = DM;
    s = w2 + (size_t)e * R * C; d = w2t + (size_t)e * R * C;
    c0 = (rem & 15) * 64; r0 = (rem >> 4) * 64;
  }

  __shared__ float tile[64][65];
  int t = threadIdx.x;
  #pragma unroll
  for (int i = 0; i < 4; ++i) {
    int idx = i * 256 + t;
    int r = idx >> 4, c4 = (idx & 15) * 4;
    float4 v = *(const float4*)(s + (size_t)(r0 + r) * C + c0 + c4);
    tile[r][c4]   = v.x; tile[r][c4+1] = v.y;
    tile[r][c4+2] = v.z; tile[r][c4+3] = v.w;
  }
  __syncthreads();
  #pragma unroll
  for (int i = 0; i < 2; ++i) {
    int idx = i * 256 + t;
    int c = idx >> 3, r8 = (idx & 7) * 8;
    bf16x8 pk;
    #pragma unroll
    for (int k = 0; k < 8; ++k) pk[k] = (bf16_t)tile[r8 + k][c];
    *(bf16x8*)(d + (size_t)(c0 + c) * R + r0 + r8) = pk;
  }
}

// ============================ tiny serial kernels ============================
__global__ void k_finalize(int* __restrict__ meta, float* __restrict__ aux_out) {
  if (threadIdx.x == 0 && blockIdx.x == 0) {
    int acc = 0;
    for (int e = 0; e < 8; ++e) { meta[24 + e] = acc; acc += meta[8 + e]; }
    const float* probsum = (const float*)(meta + 32);
    const float* zsum    = (const float*)(meta + 40);
    float s = 0.f;
    for (int e = 0; e < 8; ++e)
      s += ((float)meta[e] * (1.f / 8192.f)) * (probsum[e] * (1.f / 8192.f));
    aux_out[0] = 8.f * s * 0.01f + (zsum[0] * (1.f / 8192.f)) * 0.001f;
  }
}

__global__ __launch_bounds__(256) void k_assign(
    const int* __restrict__ eidx, float* __restrict__ gts,
    int* __restrict__ meta, int* __restrict__ list, float* __restrict__ gl,
    int* __restrict__ t2s)
{
  int t = blockIdx.x * 256 + threadIdx.x;
  int* cursor = meta + 16;
  const int* off = meta + 24;
  #pragma unroll
  for (int k = 0; k < 2; ++k) {
    int e = eidx[t*2 + k];
    float g = gts[t*2 + k];          // read before aliased write
    int pos = atomicAdd(&cursor[e], 1);
    int slot = off[e] + pos;
    list[slot] = t;
    gl[slot] = g;
    t2s[t*2 + k] = slot;
  }
}

// ====== 256x256 grouped GEMM, 4-phase/K-tile, READS-BEFORE-BARRIER (m201-style) ======
// 8 waves (2Mx4N), per-wave 128x64. LDS 128KB dynamic: buf P @P*65536;
// regions (16KB): A_ks0 @0, A_ks1 @16384, B_ks0 @32768, B_ks1 @49152.
// Line-pair swizzle (0 conflicts, R7). Pre-swizzled global src + linear gload dest.
//
// Phase q = {ds_reads(q) [pre-barrier!]; stage ONE quarter of tile t+1; [VW(4) at
// phases 1,3]; s_barrier; setprio(1) 16 MFMA setprio(0); s_barrier}. NO sched_barrier;
// compiler inserts fine lgkmcnt for the reads->MFMA dep. Mechanism: phase q+1's reads
// issue right after phase q's MFMA issue, completing under barrier jitter instead of
// bursting post-barrier (the R9-R11 serializer).
// Landing ledger (2 loads/phase FIFO): quarter staged at phase s is landed once VW(4)
// at phase s+3 retires (4 younger loads excluded), one barrier before its pre-barrier
// read at phase s+4. Stage targets are overwritten >=8 barriers after their last read.
// Tail tile: no stage; VW(0) at its phase 1 covers A_ks1/B_ks1.

#define BAR __builtin_amdgcn_s_barrier()
#define VW(N) asm volatile("s_waitcnt vmcnt(" #N ")" ::: "memory")

#define STG_A(T, KS, P) do { \
  gload16(sAq[0] + (T)*64 + (KS)*32, smem + (P)*65536 + (KS)*16384 + dq[0]); \
  gload16(sAq[1] + (T)*64 + (KS)*32, smem + (P)*65536 + (KS)*16384 + dq[1]); } while (0)
#define STG_B(T, KS, P) do { \
  gload16(sBq[0] + (T)*64 + (KS)*32, smem + (P)*65536 + 32768 + (KS)*16384 + dq[0]); \
  gload16(sBq[1] + (T)*64 + (KS)*32, smem + (P)*65536 + 32768 + (KS)*16384 + dq[1]); } while (0)

#define LDA_(AF, P, KS) do { _Pragma("unroll") for (int i_ = 0; i_ < 8; ++i_) \
  AF[i_] = *(const bf16x8*)(smem + (P)*65536 + (KS)*16384 + a_off[i_]); } while (0)
#define LDBA(P, KS) do { \
  bfrA0 = *(const bf16x8*)(smem + (P)*65536 + 32768 + (KS)*16384 + b_off[0]); \
  bfrA1 = *(const bf16x8*)(smem + (P)*65536 + 32768 + (KS)*16384 + b_off[1]); } while (0)
#define LDBB(P, KS) do { \
  bfrB0 = *(const bf16x8*)(smem + (P)*65536 + 32768 + (KS)*16384 + b_off[2]); \
  bfrB1 = *(const bf16x8*)(smem + (P)*65536 + 32768 + (KS)*16384 + b_off[3]); } while (0)

#define FMAQ(AF, B0, B1, NH) do { __builtin_amdgcn_s_setprio(1); \
  _Pragma("unroll") for (int i_ = 0; i_ < 8; ++i_) { \
    acc[i_][(NH)*2+0] = mfma_bf16(AF[i_], B0, acc[i_][(NH)*2+0]); \
    acc[i_][(NH)*2+1] = mfma_bf16(AF[i_], B1, acc[i_][(NH)*2+1]); } \
  __builtin_amdgcn_s_setprio(0); } while (0)

#define TILE(T, P) do { \
  LDA_(afr0, P, 0); LDBA(P, 0); STG_A((T)+1, 0, (P)^1); BAR; \
  FMAQ(afr0, bfrA0, bfrA1, 0); BAR; \
  LDBB(P, 0); STG_B((T)+1, 0, (P)^1); VW(4); BAR; \
  FMAQ(afr0, bfrB0, bfrB1, 1); BAR; \
  LDA_(afr1, P, 1); LDBA(P, 1); STG_A((T)+1, 1, (P)^1); BAR; \
  FMAQ(afr1, bfrA0, bfrA1, 0); BAR; \
  LDBB(P, 1); STG_B((T)+1, 1, (P)^1); VW(4); BAR; \
  FMAQ(afr1, bfrB0, bfrB1, 1); BAR; \
} while (0)

#define TAIL(P) do { \
  LDA_(afr0, P, 0); LDBA(P, 0); BAR; FMAQ(afr0, bfrA0, bfrA1, 0); BAR; \
  LDBB(P, 0); VW(0); BAR; FMAQ(afr0, bfrB0, bfrB1, 1); BAR; \
  LDA_(afr1, P, 1); LDBA(P, 1); BAR; FMAQ(afr1, bfrA0, bfrA1, 0); BAR; \
  LDBB(P, 1); BAR; FMAQ(afr1, bfrB0, bfrB1, 1); BAR; \
} while (0)

#define GEMM_PIPE(NT) do { \
  STG_A(0, 0, 0); STG_B(0, 0, 0); STG_A(0, 1, 0); STG_B(0, 1, 0); \
  VW(4); BAR; \
  for (int t_ = 0; t_ + 2 < (NT); t_ += 2) { TILE(t_, 0); TILE(t_ + 1, 1); } \
  TILE((NT) - 2, 0); \
  TAIL(1); \
} while (0)

// ============ GEMM1: H = gelu(Xn[list] @ W1t^T + b1), K=DM (NT=16) ============
__global__ __launch_bounds__(512, 1) void k_ffn1(
    const bf16_t* __restrict__ xn, const bf16_t* __restrict__ w1t,
    const float* __restrict__ b1, bf16_t* __restrict__ H,
    const int* __restrict__ list, const int* __restrict__ meta)
{
  extern __shared__ char smem[];
  int e = blockIdx.z;
  int cnt = meta[8 + e];
  int m0 = blockIdx.y * 256;
  if (m0 >= cnt) return;
  int offe = meta[24 + e];
  int n0 = blockIdx.x * 256;

  int tid = threadIdx.x, lane = tid & 63, wv = tid >> 6;
  int wm = wv >> 2, wn = wv & 3;

  const bf16_t* sAq[2]; const bf16_t* sBq[2];
  unsigned dq[2];
  #pragma unroll
  for (int i = 0; i < 2; ++i) {
    int s = i * 512 + tid;
    int line = s >> 3, u = s & 7, w = u ^ (line & 7);
    int row = (line << 1) | (w >> 2), ch = w & 3;
    int mrow = min(m0 + row, cnt - 1);
    int token = list[offe + mrow];
    sAq[i] = xn + (size_t)token * DM + ch * 8;
    sBq[i] = w1t + ((size_t)e * DF + n0 + row) * DM + ch * 8;
    dq[i] = (unsigned)(i * 8192 + wv * 1024);
  }

  unsigned a_off[8], b_off[4];
  #pragma unroll
  for (int i = 0; i < 8; ++i) a_off[i] = swz_off(wm * 128 + i * 16 + (lane & 15), lane >> 4);
  #pragma unroll
  for (int j = 0; j < 4; ++j)
    b_off[j] = swz_off(wn * 64 + (j >> 1) * 32 + (j & 1) * 16 + (lane & 15), lane >> 4);

  f32x4 acc[8][4];
  #pragma unroll
  for (int i = 0; i < 8; ++i)
    #pragma unroll
    for (int j = 0; j < 4; ++j)
      acc[i][j] = (f32x4){0.f, 0.f, 0.f, 0.f};
  bf16x8 afr0[8], afr1[8], bfrA0, bfrA1, bfrB0, bfrB1;

  GEMM_PIPE(DM / 64);

  // -------- vectorized epilogue: acc -> LDS (gelu'd bf16) -> coalesced bf16x8 stores ----
  __syncthreads();  // all waves done reading pipeline LDS
  unsigned wbase = (unsigned)(wv * 18432);           // 128 rows x 144 B
  int rq = (lane >> 4) << 2;
  #pragma unroll
  for (int i = 0; i < 8; ++i) {
    #pragma unroll
    for (int j = 0; j < 4; ++j) {
      int colL = (j >> 1) * 32 + (j & 1) * 16 + (lane & 15);
      float bb = b1[e * DF + n0 + wn * 64 + colL];
      #pragma unroll
      for (int q = 0; q < 4; ++q) {
        int rowL = i * 16 + rq + q;
        float hv = acc[i][j][q] + bb;
        hv = 0.5f * hv * (1.f + erf_fast(hv * 0.70710678118f));
        *(bf16_t*)(smem + wbase + rowL * 144 + colL * 2) = (bf16_t)hv;
      }
    }
  }
  __syncthreads();
  #pragma unroll
  for (int it = 0; it < 16; ++it) {
    int slot = it * 64 + lane;
    int rowL = slot >> 3, chunk = slot & 7;
    int mg = m0 + wm * 128 + rowL;
    if (mg < cnt) {
      bf16x8 vv = *(const bf16x8*)(smem + wbase + rowL * 144 + chunk * 16);
      *(bf16x8*)(&H[(size_t)(offe + mg) * DF + n0 + wn * 64 + chunk * 8]) = vv;
    }
  }
}

// ============ GEMM2: Y[slot] = H[slot] @ W2t^T + b2 (bf16), K=DF (NT=64) ============
__global__ __launch_bounds__(512, 1) void k_ffn2(
    const bf16_t* __restrict__ H, const bf16_t* __restrict__ w2t,
    const float* __restrict__ b2, bf16_t* __restrict__ Y,
    const int* __restrict__ meta)
{
  extern __shared__ char smem[];
  int e = blockIdx.z;
  int cnt = meta[8 + e];
  int m0 = blockIdx.y * 256;
  if (m0 >= cnt) return;
  int offe = meta[24 + e];
  int n0 = blockIdx.x * 256;

  int tid = threadIdx.x, lane = tid & 63, wv = tid >> 6;
  int wm = wv >> 2, wn = wv & 3;

  const bf16_t* sAq[2]; const bf16_t* sBq[2];
  unsigned dq[2];
  #pragma unroll
  for (int i = 0; i < 2; ++i) {
    int s = i * 512 + tid;
    int line = s >> 3, u = s & 7, w = u ^ (line & 7);
    int row = (line << 1) | (w >> 2), ch = w & 3;
    int mrow = min(m0 + row, cnt - 1);
    sAq[i] = H + (size_t)(offe + mrow) * DF + ch * 8;
    sBq[i] = w2t + ((size_t)e * DM + n0 + row) * DF + ch * 8;
    dq[i] = (unsigned)(i * 8192 + wv * 1024);
  }

  unsigned a_off[8], b_off[4];
  #pragma unroll
  for (int i = 0; i < 8; ++i) a_off[i] = swz_off(wm * 128 + i * 16 + (lane & 15), lane >> 4);
  #pragma unroll
  for (int j = 0; j < 4; ++j)
    b_off[j] = swz_off(wn * 64 + (j >> 1) * 32 + (j & 1) * 16 + (lane & 15), lane >> 4);

  f32x4 acc[8][4];
  #pragma unroll
  for (int i = 0; i < 8; ++i)
    #pragma unroll
    for (int j = 0; j < 4; ++j)
      acc[i][j] = (f32x4){0.f, 0.f, 0.f, 0.f};
  bf16x8 afr0[8], afr1[8], bfrA0, bfrA1, bfrB0, bfrB1;

  GEMM_PIPE(DF / 64);

  // -------- vectorized epilogue --------
  __syncthreads();
  unsigned wbase = (unsigned)(wv * 18432);
  int rq = (lane >> 4) << 2;
  #pragma unroll
  for (int i = 0; i < 8; ++i) {
    #pragma unroll
    for (int j = 0; j < 4; ++j) {
      int colL = (j >> 1) * 32 + (j & 1) * 16 + (lane & 15);
      float bb = b2[e * DM + n0 + wn * 64 + colL];
      #pragma unroll
      for (int q = 0; q < 4; ++q) {
        int rowL = i * 16 + rq + q;
        *(bf16_t*)(smem + wbase + rowL * 144 + colL * 2) = (bf16_t)(acc[i][j][q] + bb);
      }
    }
  }
  __syncthreads();
  #pragma unroll
  for (int it = 0; it < 16; ++it) {
    int slot = it * 64 + lane;
    int rowL = slot >> 3, chunk = slot & 7;
    int mg = m0 + wm * 128 + rowL;
    if (mg < cnt) {
      bf16x8 vv = *(const bf16x8*)(smem + wbase + rowL * 144 + chunk * 16);
      *(bf16x8*)(&Y[(size_t)(offe + mg) * DM + n0 + wn * 64 + chunk * 8]) = vv;
    }
  }
}

// ===== combine: out[t] += g0*Y[s0] + g1*Y[s1] (one wave per token, bf16 Y) =====
__global__ __launch_bounds__(256) void k_combine(
    const bf16_t* __restrict__ Y, const int* __restrict__ t2s,
    const float* __restrict__ gl, float* __restrict__ out)
{
  int lane = threadIdx.x & 63, wv = threadIdx.x >> 6;
  int t = blockIdx.x * 4 + wv;
  int s0 = t2s[t*2], s1 = t2s[t*2 + 1];
  float g0 = gl[s0], g1 = gl[s1];
  const bf16_t* y0 = Y + (size_t)s0 * DM;
  const bf16_t* y1 = Y + (size_t)s1 * DM;
  float* o = out + (size_t)t * DM;
  #pragma unroll
  for (int c = 0; c < 4; ++c) {
    int d = c * 256 + lane * 4;
    float4 r  = *(const float4*)(o + d);
    bf16x4 a = *(const bf16x4*)(y0 + d);
    bf16x4 b = *(const bf16x4*)(y1 + d);
    r.x += g0 * (float)a[0] + g1 * (float)b[0];
    r.y += g0 * (float)a[1] + g1 * (float)b[1];
    r.z += g0 * (float)a[2] + g1 * (float)b[2];
    r.w += g0 * (float)a[3] + g1 * (float)b[3];
    *(float4*)(o + d) = r;
  }
}

// ============================ launch ============================
extern "C" void kernel_launch(void* const* d_in, const int* in_sizes, int n_in,
                              void* d_out, int out_size, void* d_ws, size_t ws_size,
                              hipStream_t stream) {
  const float* x      = (const float*)d_in[0];
  const float* gate_w = (const float*)d_in[1];
  const float* ln_g   = (const float*)d_in[2];
  const float* ln_b   = (const float*)d_in[3];
  const float* w1     = (const float*)d_in[4];
  const float* b1     = (const float*)d_in[5];
  const float* w2     = (const float*)d_in[6];
  const float* b2     = (const float*)d_in[7];
  float* out = (float*)d_out;

  char* ws = (char*)d_ws;
  bf16_t* xn   = (bf16_t*)(ws);                                  // 16 MiB
  bf16_t* w1t  = (bf16_t*)(ws + 16777216ull);                    // 64 MiB [E][F][D]; dead after ffn1
  bf16_t* Y    = (bf16_t*)(ws + 16777216ull);                    //   reused: Y [NP][DM] bf16 (32 MiB)
  bf16_t* w2t  = (bf16_t*)(ws + 83886080ull);                    // 64 MiB [E][D][F]
  bf16_t* H    = (bf16_t*)(ws + 150994944ull);                   // 128 MiB [NP][F]
  int*    list = (int*)   (ws + 285212672ull);
  float*  gl   = (float*) (ws + 285278208ull);
  int*    eidx = (int*)   (ws + 285343744ull);
  float*  gts  = (float*) (ws + 285409280ull);                   // aliased as t2s after k_assign
  int*    t2s  = (int*)   (ws + 285409280ull);
  int*    meta = (int*)   (ws + 285474816ull);

  hipFuncSetAttribute((const void*)k_ffn1, hipFuncAttributeMaxDynamicSharedMemorySize, 147456);
  hipFuncSetAttribute((const void*)k_ffn2, hipFuncAttributeMaxDynamicSharedMemorySize, 147456);

  hipMemsetAsync(meta, 0, 256, stream);
  k_router<<<T_TOK / 4, 256, 0, stream>>>(x, gate_w, ln_g, ln_b, out, xn, eidx, gts, meta);
  k_convT2<<<16384, 256, 0, stream>>>(w1, w1t, w2, w2t);
  k_finalize<<<1, 1, 0, stream>>>(meta, out + (size_t)T_TOK * DM);
  k_assign<<<T_TOK / 256, 256, 0, stream>>>(eidx, gts, meta, list, gl, t2s);
  k_ffn1<<<dim3(DF / 256, 32, NE), 512, 147456, stream>>>(xn, w1t, b1, H, list, meta);
  k_ffn2<<<dim3(DM / 256, 32, NE), 512, 147456, stream>>>(H, w2t, b2, Y, meta);
  k_combine<<<T_TOK / 4, 256, 0, stream>>>(Y, t2s, gl, out);
}

// Round 13
// 667.407 us; speedup vs baseline: 1.0052x; 1.0052x over previous
//
#include <hip/hip_runtime.h>
#include <math.h>

typedef __bf16 bf16_t;
typedef bf16_t bf16x8 __attribute__((ext_vector_type(8)));
typedef bf16_t bf16x4 __attribute__((ext_vector_type(4)));
typedef float  f32x4  __attribute__((ext_vector_type(4)));

#define T_TOK 8192
#define DM 1024
#define DF 4096
#define NE 8
#define NP 16384  // total token-expert pairs = T_TOK * 2

__device__ __forceinline__ f32x4 mfma_bf16(bf16x8 a, bf16x8 b, f32x4 c) {
  return __builtin_amdgcn_mfma_f32_16x16x32_bf16(a, b, c, 0, 0, 0);
}

__device__ __forceinline__ void gload16(const void* g, void* l) {
  __builtin_amdgcn_global_load_lds((const __attribute__((address_space(1))) void*)g,
                                   (__attribute__((address_space(3))) void*)l, 16, 0, 0);
}

// Abramowitz-Stegun 7.1.26 erf, |err| <= 1.5e-7
__device__ __forceinline__ float erf_fast(float x) {
  float ax = fabsf(x);
  float t = 1.f / (1.f + 0.3275911f * ax);
  float p = t * (0.254829592f + t * (-0.284496736f + t * (1.421413741f +
            t * (-1.453152027f + t * 1.061405429f))));
  float r = 1.f - p * __expf(-ax * ax);
  return copysignf(r, x);
}

// Line-pair LDS swizzle within a [rows][32 k] bf16 subtile (64B rows).
// byte(row,ch) = (row>>1)*128 + ((((row&1)<<2)|ch) ^ ((row>>1)&7))*16  [R7: 0 conflicts]
__device__ __forceinline__ unsigned swz_off(int row, int ch) {
  return (unsigned)(((row >> 1) << 7) + (((((row & 1) << 2) | ch) ^ ((row >> 1) & 7)) << 4));
}

// meta layout (ints): [0..7]=cnt1 [8..15]=cnt2 [16..23]=cursor [24..31]=off
// [32..39]=probsum(float) [40]=zsum(float)

// ============================ router ============================
__global__ __launch_bounds__(256) void k_router(
    const float* __restrict__ x, const float* __restrict__ gate_w,
    const float* __restrict__ ln_g, const float* __restrict__ ln_b,
    float* __restrict__ out, bf16_t* __restrict__ xn,
    int* __restrict__ eidx, float* __restrict__ gts, int* __restrict__ meta)
{
  int* cnt1 = meta;
  int* cnt2 = meta + 8;
  float* probsum = (float*)(meta + 32);
  float* zsum    = (float*)(meta + 40);

  __shared__ float sprob[8];
  __shared__ float sz;
  __shared__ int sc1[8], sc2[8];
  if (threadIdx.x < 8) { sprob[threadIdx.x] = 0.f; sc1[threadIdx.x] = 0; sc2[threadIdx.x] = 0; }
  if (threadIdx.x == 8) sz = 0.f;
  __syncthreads();

  int lane = threadIdx.x & 63, wv = threadIdx.x >> 6;
  int t = blockIdx.x * 4 + wv;
  const float* xt = x + (size_t)t * DM;

  float4 v[4];
  float s1 = 0.f, s2 = 0.f;
  #pragma unroll
  for (int c = 0; c < 4; ++c) {
    v[c] = *(const float4*)(xt + c * 256 + lane * 4);
    s1 += v[c].x + v[c].y + v[c].z + v[c].w;
    s2 += v[c].x * v[c].x + v[c].y * v[c].y + v[c].z * v[c].z + v[c].w * v[c].w;
  }
  #pragma unroll
  for (int o = 32; o > 0; o >>= 1) { s1 += __shfl_xor(s1, o, 64); s2 += __shfl_xor(s2, o, 64); }
  float mu = s1 * (1.f / DM);
  float var = s2 * (1.f / DM) - mu * mu;
  float rstd = rsqrtf(var + 1e-5f);

  float xv[16];
  #pragma unroll
  for (int c = 0; c < 4; ++c) {
    int d = c * 256 + lane * 4;
    float4 g4 = *(const float4*)(ln_g + d);
    float4 b4 = *(const float4*)(ln_b + d);
    xv[c*4+0] = (v[c].x - mu) * rstd * g4.x + b4.x;
    xv[c*4+1] = (v[c].y - mu) * rstd * g4.y + b4.y;
    xv[c*4+2] = (v[c].z - mu) * rstd * g4.z + b4.z;
    xv[c*4+3] = (v[c].w - mu) * rstd * g4.w + b4.w;
    *(float4*)(out + (size_t)t * DM + d) = v[c];  // residual init
    bf16x4 pk = { (bf16_t)xv[c*4+0], (bf16_t)xv[c*4+1], (bf16_t)xv[c*4+2], (bf16_t)xv[c*4+3] };
    *(bf16x4*)(xn + (size_t)t * DM + d) = pk;
  }

  float lg[8];
  #pragma unroll
  for (int e = 0; e < 8; ++e) {
    float p = 0.f;
    #pragma unroll
    for (int c = 0; c < 4; ++c) {
      int d = c * 256 + lane * 4;
      float4 g4 = *(const float4*)(gate_w + e * DM + d);
      p += xv[c*4+0] * g4.x + xv[c*4+1] * g4.y + xv[c*4+2] * g4.z + xv[c*4+3] * g4.w;
    }
    #pragma unroll
    for (int o = 32; o > 0; o >>= 1) p += __shfl_xor(p, o, 64);
    lg[e] = p;
  }

  if (lane == 0) {
    float m = -1e30f;
    #pragma unroll
    for (int e = 0; e < 8; ++e) { lg[e] = fminf(fmaxf(lg[e], -10.f), 10.f); m = fmaxf(m, lg[e]); }
    float pr[8]; float se = 0.f;
    #pragma unroll
    for (int e = 0; e < 8; ++e) { pr[e] = expf(lg[e] - m); se += pr[e]; }
    float inv = 1.f / se;
    #pragma unroll
    for (int e = 0; e < 8; ++e) pr[e] *= inv;
    float lse = m + logf(se);

    int e0 = 0; float p0 = pr[0];
    #pragma unroll
    for (int e = 1; e < 8; ++e) if (pr[e] > p0) { p0 = pr[e]; e0 = e; }
    int e1 = -1; float p1 = -1.f;
    #pragma unroll
    for (int e = 0; e < 8; ++e) if (e != e0 && pr[e] > p1) { p1 = pr[e]; e1 = e; }
    float s = p0 + p1 + 1e-8f;
    eidx[t*2]   = e0; eidx[t*2+1] = e1;
    gts[t*2]    = p0 / s; gts[t*2+1] = p1 / s;

    atomicAdd(&sc1[e0], 1);
    atomicAdd(&sc2[e0], 1);
    atomicAdd(&sc2[e1], 1);
    #pragma unroll
    for (int e = 0; e < 8; ++e) atomicAdd(&sprob[e], pr[e]);
    atomicAdd(&sz, lse * lse);
  }
  __syncthreads();
  if (threadIdx.x < 8) {
    if (sc1[threadIdx.x]) atomicAdd(&cnt1[threadIdx.x], sc1[threadIdx.x]);
    if (sc2[threadIdx.x]) atomicAdd(&cnt2[threadIdx.x], sc2[threadIdx.x]);
    atomicAdd(&probsum[threadIdx.x], sprob[threadIdx.x]);
  }
  if (threadIdx.x == 8) atomicAdd(zsum, sz);
}

// ========== merged weight convert+transpose (w1 and w2 in one grid) ==========
__global__ __launch_bounds__(256) void k_convT2(
    const float* __restrict__ w1, bf16_t* __restrict__ w1t,
    const float* __restrict__ w2, bf16_t* __restrict__ w2t)
{
  int bid = blockIdx.x;
  const float* s; bf16_t* d; int R, C, c0, r0;
  if (bid < 8192) {
    int e = bid >> 10, rem = bid & 1023;
    R = DM; C = DF;
    s = w1 + (size_t)e * R * C; d = w1t + (size_t)e * R * C;
    c0 = (rem & 63) * 64; r0 = (rem >> 6) * 64;
  } else {
    int e = (bid - 8192) >> 10, rem = (bid - 8192) & 1023;
    R = DF; C = DM;
    s = w2 + (size_t)e * R * C; d = w2t + (size_t)e * R * C;
    c0 = (rem & 15) * 64; r0 = (rem >> 4) * 64;
  }

  __shared__ float tile[64][65];
  int t = threadIdx.x;
  #pragma unroll
  for (int i = 0; i < 4; ++i) {
    int idx = i * 256 + t;
    int r = idx >> 4, c4 = (idx & 15) * 4;
    float4 v = *(const float4*)(s + (size_t)(r0 + r) * C + c0 + c4);
    tile[r][c4]   = v.x; tile[r][c4+1] = v.y;
    tile[r][c4+2] = v.z; tile[r][c4+3] = v.w;
  }
  __syncthreads();
  #pragma unroll
  for (int i = 0; i < 2; ++i) {
    int idx = i * 256 + t;
    int c = idx >> 3, r8 = (idx & 7) * 8;
    bf16x8 pk;
    #pragma unroll
    for (int k = 0; k < 8; ++k) pk[k] = (bf16_t)tile[r8 + k][c];
    *(bf16x8*)(d + (size_t)(c0 + c) * R + r0 + r8) = pk;
  }
}

// ============================ tiny serial kernels ============================
__global__ void k_finalize(int* __restrict__ meta, float* __restrict__ aux_out) {
  if (threadIdx.x == 0 && blockIdx.x == 0) {
    int acc = 0;
    for (int e = 0; e < 8; ++e) { meta[24 + e] = acc; acc += meta[8 + e]; }
    const float* probsum = (const float*)(meta + 32);
    const float* zsum    = (const float*)(meta + 40);
    float s = 0.f;
    for (int e = 0; e < 8; ++e)
      s += ((float)meta[e] * (1.f / 8192.f)) * (probsum[e] * (1.f / 8192.f));
    aux_out[0] = 8.f * s * 0.01f + (zsum[0] * (1.f / 8192.f)) * 0.001f;
  }
}

__global__ __launch_bounds__(256) void k_assign(
    const int* __restrict__ eidx, float* __restrict__ gts,
    int* __restrict__ meta, int* __restrict__ list, float* __restrict__ gl,
    int* __restrict__ t2s)
{
  int t = blockIdx.x * 256 + threadIdx.x;
  int* cursor = meta + 16;
  const int* off = meta + 24;
  #pragma unroll
  for (int k = 0; k < 2; ++k) {
    int e = eidx[t*2 + k];
    float g = gts[t*2 + k];          // read before aliased write
    int pos = atomicAdd(&cursor[e], 1);
    int slot = off[e] + pos;
    list[slot] = t;
    gl[slot] = g;
    t2s[t*2 + k] = slot;
  }
}

// ====== grouped GEMM: 128x256 tile, BK=32, 8 waves (2Mx4N), per-wave 64x64 ======
// TLP-first config: 48 KB static LDS dbuf + __launch_bounds__(512,4) (VGPR<=128)
// -> 2 blocks/CU = 16 waves/CU = 4 waves/SIMD. Independent blocks hide each
// other's barrier/latency stalls (m114) instead of intra-block choreography.
// LDS buf P @ P*24576: A[128][32] @0 (8KB), B[256][32] @8192 (16KB); line-pair
// swizzle (0 conflicts, R7-verified); pre-swizzled per-lane global src + linear
// gload_lds dest (rule #21 both-sides). 3 gloads/thread/K-tile.
// Loop: STG(t+1 -> P^1); VW(3) [t landed, t+1 flying]; BAR; 8 ds_read + 16 MFMA
// (setprio); BAR. VW(0) only at tail. RAW: own VW+BAR. WAR: P^1's readers'
// lgkm-waits complete before MFMA issue, hence before the closing BAR that
// precedes any restage of P^1.

#define BAR __builtin_amdgcn_s_barrier()
#define VW(N) asm volatile("s_waitcnt vmcnt(" #N ")" ::: "memory")

#define STG(T, P) do { \
  gload16(sA  + (size_t)(T) * 32, smem + (P) * 24576 +         wv * 1024); \
  gload16(sB0 + (size_t)(T) * 32, smem + (P) * 24576 +  8192 + wv * 1024); \
  gload16(sB1 + (size_t)(T) * 32, smem + (P) * 24576 + 16384 + wv * 1024); } while (0)

#define COMP(P) do { \
  bf16x8 afr[4], bfr[4]; \
  _Pragma("unroll") for (int i_ = 0; i_ < 4; ++i_) \
    afr[i_] = *(const bf16x8*)(smem + (P) * 24576 + a_off[i_]); \
  _Pragma("unroll") for (int j_ = 0; j_ < 4; ++j_) \
    bfr[j_] = *(const bf16x8*)(smem + (P) * 24576 + 8192 + b_off[j_]); \
  __builtin_amdgcn_s_setprio(1); \
  _Pragma("unroll") for (int i_ = 0; i_ < 4; ++i_) \
    _Pragma("unroll") for (int j_ = 0; j_ < 4; ++j_) \
      acc[i_][j_] = mfma_bf16(afr[i_], bfr[j_], acc[i_][j_]); \
  __builtin_amdgcn_s_setprio(0); } while (0)

#define KLOOP(NT) do { \
  STG(0, 0); \
  for (int kt = 0; kt < (NT); kt += 2) { \
    if (kt + 1 < (NT)) { STG(kt + 1, 1); VW(3); } else { VW(0); } \
    BAR; COMP(0); BAR; \
    if (kt + 2 < (NT)) { STG(kt + 2, 0); VW(3); } else { VW(0); } \
    BAR; COMP(1); BAR; \
  } \
} while (0)

// ============ GEMM1: H = gelu(Xn[list] @ W1t^T + b1), K=DM (NT=32) ============
__global__ __launch_bounds__(512, 4) void k_ffn1(
    const bf16_t* __restrict__ xn, const bf16_t* __restrict__ w1t,
    const float* __restrict__ b1, bf16_t* __restrict__ H,
    const int* __restrict__ list, const int* __restrict__ meta)
{
  __shared__ __align__(1024) char smem[49152];
  int e = blockIdx.z;
  int cnt = meta[8 + e];
  int m0 = blockIdx.y * 128;
  if (m0 >= cnt) return;
  int offe = meta[24 + e];
  int n0 = blockIdx.x * 256;

  int tid = threadIdx.x, lane = tid & 63, wv = tid >> 6;
  int wm = wv >> 2, wn = wv & 3;

  // staging sources: A 512 slots (1/thread), B 1024 slots (2/thread)
  const bf16_t* sA; const bf16_t* sB0; const bf16_t* sB1;
  {
    int s = tid, line = s >> 3, u = s & 7, w = u ^ (line & 7);
    int row = (line << 1) | (w >> 2), ch = w & 3;
    int mrow = min(m0 + row, cnt - 1);
    int token = list[offe + mrow];
    sA = xn + (size_t)token * DM + ch * 8;
  }
  {
    int s = tid, line = s >> 3, u = s & 7, w = u ^ (line & 7);
    int row = (line << 1) | (w >> 2), ch = w & 3;
    sB0 = w1t + ((size_t)e * DF + n0 + row) * DM + ch * 8;
  }
  {
    int s = 512 + tid, line = s >> 3, u = s & 7, w = u ^ (line & 7);
    int row = (line << 1) | (w >> 2), ch = w & 3;
    sB1 = w1t + ((size_t)e * DF + n0 + row) * DM + ch * 8;
  }

  unsigned a_off[4], b_off[4];
  #pragma unroll
  for (int i = 0; i < 4; ++i) a_off[i] = swz_off(wm * 64 + i * 16 + (lane & 15), lane >> 4);
  #pragma unroll
  for (int j = 0; j < 4; ++j) b_off[j] = swz_off(wn * 64 + j * 16 + (lane & 15), lane >> 4);

  f32x4 acc[4][4];
  #pragma unroll
  for (int i = 0; i < 4; ++i)
    #pragma unroll
    for (int j = 0; j < 4; ++j)
      acc[i][j] = (f32x4){0.f, 0.f, 0.f, 0.f};

  KLOOP(DM / 32);

  int rbase = wm * 64 + ((lane >> 4) << 2);
  int cbase = n0 + wn * 64 + (lane & 15);
  #pragma unroll
  for (int i = 0; i < 4; ++i) {
    #pragma unroll
    for (int q = 0; q < 4; ++q) {
      int mg = m0 + rbase + i * 16 + q;
      if (mg < cnt) {
        size_t hrow = (size_t)(offe + mg) * DF;
        #pragma unroll
        for (int j = 0; j < 4; ++j) {
          int col = cbase + j * 16;
          float hv = acc[i][j][q] + b1[e * DF + col];
          hv = 0.5f * hv * (1.f + erf_fast(hv * 0.70710678118f));
          H[hrow + col] = (bf16_t)hv;
        }
      }
    }
  }
}

// ============ GEMM2: Y[slot] = H[slot] @ W2t^T + b2 (bf16), K=DF (NT=128) ============
__global__ __launch_bounds__(512, 4) void k_ffn2(
    const bf16_t* __restrict__ H, const bf16_t* __restrict__ w2t,
    const float* __restrict__ b2, bf16_t* __restrict__ Y,
    const int* __restrict__ meta)
{
  __shared__ __align__(1024) char smem[49152];
  int e = blockIdx.z;
  int cnt = meta[8 + e];
  int m0 = blockIdx.y * 128;
  if (m0 >= cnt) return;
  int offe = meta[24 + e];
  int n0 = blockIdx.x * 256;

  int tid = threadIdx.x, lane = tid & 63, wv = tid >> 6;
  int wm = wv >> 2, wn = wv & 3;

  const bf16_t* sA; const bf16_t* sB0; const bf16_t* sB1;
  {
    int s = tid, line = s >> 3, u = s & 7, w = u ^ (line & 7);
    int row = (line << 1) | (w >> 2), ch = w & 3;
    int mrow = min(m0 + row, cnt - 1);
    sA = H + (size_t)(offe + mrow) * DF + ch * 8;
  }
  {
    int s = tid, line = s >> 3, u = s & 7, w = u ^ (line & 7);
    int row = (line << 1) | (w >> 2), ch = w & 3;
    sB0 = w2t + ((size_t)e * DM + n0 + row) * DF + ch * 8;
  }
  {
    int s = 512 + tid, line = s >> 3, u = s & 7, w = u ^ (line & 7);
    int row = (line << 1) | (w >> 2), ch = w & 3;
    sB1 = w2t + ((size_t)e * DM + n0 + row) * DF + ch * 8;
  }

  unsigned a_off[4], b_off[4];
  #pragma unroll
  for (int i = 0; i < 4; ++i) a_off[i] = swz_off(wm * 64 + i * 16 + (lane & 15), lane >> 4);
  #pragma unroll
  for (int j = 0; j < 4; ++j) b_off[j] = swz_off(wn * 64 + j * 16 + (lane & 15), lane >> 4);

  f32x4 acc[4][4];
  #pragma unroll
  for (int i = 0; i < 4; ++i)
    #pragma unroll
    for (int j = 0; j < 4; ++j)
      acc[i][j] = (f32x4){0.f, 0.f, 0.f, 0.f};

  KLOOP(DF / 32);

  int rbase = wm * 64 + ((lane >> 4) << 2);
  int cbase = n0 + wn * 64 + (lane & 15);
  #pragma unroll
  for (int i = 0; i < 4; ++i) {
    #pragma unroll
    for (int q = 0; q < 4; ++q) {
      int mg = m0 + rbase + i * 16 + q;
      if (mg < cnt) {
        size_t yrow = (size_t)(offe + mg) * DM;
        #pragma unroll
        for (int j = 0; j < 4; ++j) {
          int col = cbase + j * 16;
          Y[yrow + col] = (bf16_t)(acc[i][j][q] + b2[e * DM + col]);
        }
      }
    }
  }
}

// ===== combine: out[t] += g0*Y[s0] + g1*Y[s1] (one wave per token, bf16 Y) =====
__global__ __launch_bounds__(256) void k_combine(
    const bf16_t* __restrict__ Y, const int* __restrict__ t2s,
    const float* __restrict__ gl, float* __restrict__ out)
{
  int lane = threadIdx.x & 63, wv = threadIdx.x >> 6;
  int t = blockIdx.x * 4 + wv;
  int s0 = t2s[t*2], s1 = t2s[t*2 + 1];
  float g0 = gl[s0], g1 = gl[s1];
  const bf16_t* y0 = Y + (size_t)s0 * DM;
  const bf16_t* y1 = Y + (size_t)s1 * DM;
  float* o = out + (size_t)t * DM;
  #pragma unroll
  for (int c = 0; c < 4; ++c) {
    int d = c * 256 + lane * 4;
    float4 r  = *(const float4*)(o + d);
    bf16x4 a = *(const bf16x4*)(y0 + d);
    bf16x4 b = *(const bf16x4*)(y1 + d);
    r.x += g0 * (float)a[0] + g1 * (float)b[0];
    r.y += g0 * (float)a[1] + g1 * (float)b[1];
    r.z += g0 * (float)a[2] + g1 * (float)b[2];
    r.w += g0 * (float)a[3] + g1 * (float)b[3];
    *(float4*)(o + d) = r;
  }
}

// ============================ launch ============================
extern "C" void kernel_launch(void* const* d_in, const int* in_sizes, int n_in,
                              void* d_out, int out_size, void* d_ws, size_t ws_size,
                              hipStream_t stream) {
  const float* x      = (const float*)d_in[0];
  const float* gate_w = (const float*)d_in[1];
  const float* ln_g   = (const float*)d_in[2];
  const float* ln_b   = (const float*)d_in[3];
  const float* w1     = (const float*)d_in[4];
  const float* b1     = (const float*)d_in[5];
  const float* w2     = (const float*)d_in[6];
  const float* b2     = (const float*)d_in[7];
  float* out = (float*)d_out;

  char* ws = (char*)d_ws;
  bf16_t* xn   = (bf16_t*)(ws);                                  // 16 MiB
  bf16_t* w1t  = (bf16_t*)(ws + 16777216ull);                    // 64 MiB [E][F][D]; dead after ffn1
  bf16_t* Y    = (bf16_t*)(ws + 16777216ull);                    //   reused: Y [NP][DM] bf16 (32 MiB)
  bf16_t* w2t  = (bf16_t*)(ws + 83886080ull);                    // 64 MiB [E][D][F]
  bf16_t* H    = (bf16_t*)(ws + 150994944ull);                   // 128 MiB [NP][F]
  int*    list = (int*)   (ws + 285212672ull);
  float*  gl   = (float*) (ws + 285278208ull);
  int*    eidx = (int*)   (ws + 285343744ull);
  float*  gts  = (float*) (ws + 285409280ull);                   // aliased as t2s after k_assign
  int*    t2s  = (int*)   (ws + 285409280ull);
  int*    meta = (int*)   (ws + 285474816ull);

  hipMemsetAsync(meta, 0, 256, stream);
  k_router<<<T_TOK / 4, 256, 0, stream>>>(x, gate_w, ln_g, ln_b, out, xn, eidx, gts, meta);
  k_convT2<<<16384, 256, 0, stream>>>(w1, w1t, w2, w2t);
  k_finalize<<<1, 1, 0, stream>>>(meta, out + (size_t)T_TOK * DM);
  k_assign<<<T_TOK / 256, 256, 0, stream>>>(eidx, gts, meta, list, gl, t2s);
  k_ffn1<<<dim3(DF / 256, 64, NE), 512, 0, stream>>>(xn, w1t, b1, H, list, meta);
  k_ffn2<<<dim3(DM / 256, 64, NE), 512, 0, stream>>>(H, w2t, b2, Y, meta);
  k_combine<<<T_TOK / 4, 256, 0, stream>>>(Y, t2s, gl, out);
}

// Round 14
// 644.267 us; speedup vs baseline: 1.0413x; 1.0359x over previous
//
#include <hip/hip_runtime.h>
#include <math.h>

typedef __bf16 bf16_t;
typedef bf16_t bf16x8 __attribute__((ext_vector_type(8)));
typedef bf16_t bf16x4 __attribute__((ext_vector_type(4)));
typedef float  f32x4  __attribute__((ext_vector_type(4)));

#define T_TOK 8192
#define DM 1024
#define DF 4096
#define NE 8
#define NP 16384  // total token-expert pairs = T_TOK * 2

__device__ __forceinline__ f32x4 mfma_bf16(bf16x8 a, bf16x8 b, f32x4 c) {
  return __builtin_amdgcn_mfma_f32_16x16x32_bf16(a, b, c, 0, 0, 0);
}

__device__ __forceinline__ void gload16(const void* g, void* l) {
  __builtin_amdgcn_global_load_lds((const __attribute__((address_space(1))) void*)g,
                                   (__attribute__((address_space(3))) void*)l, 16, 0, 0);
}

// Abramowitz-Stegun 7.1.26 erf, |err| <= 1.5e-7
__device__ __forceinline__ float erf_fast(float x) {
  float ax = fabsf(x);
  float t = 1.f / (1.f + 0.3275911f * ax);
  float p = t * (0.254829592f + t * (-0.284496736f + t * (1.421413741f +
            t * (-1.453152027f + t * 1.061405429f))));
  float r = 1.f - p * __expf(-ax * ax);
  return copysignf(r, x);
}

// Line-pair LDS swizzle within a [rows][32 k] bf16 subtile (64B rows).
// byte(row,ch) = (row>>1)*128 + ((((row&1)<<2)|ch) ^ ((row>>1)&7))*16  [R7: 0 conflicts]
__device__ __forceinline__ unsigned swz_off(int row, int ch) {
  return (unsigned)(((row >> 1) << 7) + (((((row & 1) << 2) | ch) ^ ((row >> 1) & 7)) << 4));
}

// meta layout (ints): [0..7]=cnt1 [8..15]=cnt2 [16..23]=cursor [24..31]=off
// [32..39]=probsum(float) [40]=zsum(float)

// ============================ router ============================
__global__ __launch_bounds__(256) void k_router(
    const float* __restrict__ x, const float* __restrict__ gate_w,
    const float* __restrict__ ln_g, const float* __restrict__ ln_b,
    float* __restrict__ out, bf16_t* __restrict__ xn,
    int* __restrict__ eidx, float* __restrict__ gts, int* __restrict__ meta)
{
  int* cnt1 = meta;
  int* cnt2 = meta + 8;
  float* probsum = (float*)(meta + 32);
  float* zsum    = (float*)(meta + 40);

  __shared__ float sprob[8];
  __shared__ float sz;
  __shared__ int sc1[8], sc2[8];
  if (threadIdx.x < 8) { sprob[threadIdx.x] = 0.f; sc1[threadIdx.x] = 0; sc2[threadIdx.x] = 0; }
  if (threadIdx.x == 8) sz = 0.f;
  __syncthreads();

  int lane = threadIdx.x & 63, wv = threadIdx.x >> 6;
  int t = blockIdx.x * 4 + wv;
  const float* xt = x + (size_t)t * DM;

  float4 v[4];
  float s1 = 0.f, s2 = 0.f;
  #pragma unroll
  for (int c = 0; c < 4; ++c) {
    v[c] = *(const float4*)(xt + c * 256 + lane * 4);
    s1 += v[c].x + v[c].y + v[c].z + v[c].w;
    s2 += v[c].x * v[c].x + v[c].y * v[c].y + v[c].z * v[c].z + v[c].w * v[c].w;
  }
  #pragma unroll
  for (int o = 32; o > 0; o >>= 1) { s1 += __shfl_xor(s1, o, 64); s2 += __shfl_xor(s2, o, 64); }
  float mu = s1 * (1.f / DM);
  float var = s2 * (1.f / DM) - mu * mu;
  float rstd = rsqrtf(var + 1e-5f);

  float xv[16];
  #pragma unroll
  for (int c = 0; c < 4; ++c) {
    int d = c * 256 + lane * 4;
    float4 g4 = *(const float4*)(ln_g + d);
    float4 b4 = *(const float4*)(ln_b + d);
    xv[c*4+0] = (v[c].x - mu) * rstd * g4.x + b4.x;
    xv[c*4+1] = (v[c].y - mu) * rstd * g4.y + b4.y;
    xv[c*4+2] = (v[c].z - mu) * rstd * g4.z + b4.z;
    xv[c*4+3] = (v[c].w - mu) * rstd * g4.w + b4.w;
    *(float4*)(out + (size_t)t * DM + d) = v[c];  // residual init
    bf16x4 pk = { (bf16_t)xv[c*4+0], (bf16_t)xv[c*4+1], (bf16_t)xv[c*4+2], (bf16_t)xv[c*4+3] };
    *(bf16x4*)(xn + (size_t)t * DM + d) = pk;
  }

  float lg[8];
  #pragma unroll
  for (int e = 0; e < 8; ++e) {
    float p = 0.f;
    #pragma unroll
    for (int c = 0; c < 4; ++c) {
      int d = c * 256 + lane * 4;
      float4 g4 = *(const float4*)(gate_w + e * DM + d);
      p += xv[c*4+0] * g4.x + xv[c*4+1] * g4.y + xv[c*4+2] * g4.z + xv[c*4+3] * g4.w;
    }
    #pragma unroll
    for (int o = 32; o > 0; o >>= 1) p += __shfl_xor(p, o, 64);
    lg[e] = p;
  }

  if (lane == 0) {
    float m = -1e30f;
    #pragma unroll
    for (int e = 0; e < 8; ++e) { lg[e] = fminf(fmaxf(lg[e], -10.f), 10.f); m = fmaxf(m, lg[e]); }
    float pr[8]; float se = 0.f;
    #pragma unroll
    for (int e = 0; e < 8; ++e) { pr[e] = expf(lg[e] - m); se += pr[e]; }
    float inv = 1.f / se;
    #pragma unroll
    for (int e = 0; e < 8; ++e) pr[e] *= inv;
    float lse = m + logf(se);

    int e0 = 0; float p0 = pr[0];
    #pragma unroll
    for (int e = 1; e < 8; ++e) if (pr[e] > p0) { p0 = pr[e]; e0 = e; }
    int e1 = -1; float p1 = -1.f;
    #pragma unroll
    for (int e = 0; e < 8; ++e) if (e != e0 && pr[e] > p1) { p1 = pr[e]; e1 = e; }
    float s = p0 + p1 + 1e-8f;
    eidx[t*2]   = e0; eidx[t*2+1] = e1;
    gts[t*2]    = p0 / s; gts[t*2+1] = p1 / s;

    atomicAdd(&sc1[e0], 1);
    atomicAdd(&sc2[e0], 1);
    atomicAdd(&sc2[e1], 1);
    #pragma unroll
    for (int e = 0; e < 8; ++e) atomicAdd(&sprob[e], pr[e]);
    atomicAdd(&sz, lse * lse);
  }
  __syncthreads();
  if (threadIdx.x < 8) {
    if (sc1[threadIdx.x]) atomicAdd(&cnt1[threadIdx.x], sc1[threadIdx.x]);
    if (sc2[threadIdx.x]) atomicAdd(&cnt2[threadIdx.x], sc2[threadIdx.x]);
    atomicAdd(&probsum[threadIdx.x], sprob[threadIdx.x]);
  }
  if (threadIdx.x == 8) atomicAdd(zsum, sz);
}

// ========== merged weight convert+transpose (w1 and w2 in one grid) ==========
__global__ __launch_bounds__(256) void k_convT2(
    const float* __restrict__ w1, bf16_t* __restrict__ w1t,
    const float* __restrict__ w2, bf16_t* __restrict__ w2t)
{
  int bid = blockIdx.x;
  const float* s; bf16_t* d; int R, C, c0, r0;
  if (bid < 8192) {
    int e = bid >> 10, rem = bid & 1023;
    R = DM; C = DF;
    s = w1 + (size_t)e * R * C; d = w1t + (size_t)e * R * C;
    c0 = (rem & 63) * 64; r0 = (rem >> 6) * 64;
  } else {
    int e = (bid - 8192) >> 10, rem = (bid - 8192) & 1023;
    R = DF; C = DM;
    s = w2 + (size_t)e * R * C; d = w2t + (size_t)e * R * C;
    c0 = (rem & 15) * 64; r0 = (rem >> 4) * 64;
  }

  __shared__ float tile[64][65];
  int t = threadIdx.x;
  #pragma unroll
  for (int i = 0; i < 4; ++i) {
    int idx = i * 256 + t;
    int r = idx >> 4, c4 = (idx & 15) * 4;
    float4 v = *(const float4*)(s + (size_t)(r0 + r) * C + c0 + c4);
    tile[r][c4]   = v.x; tile[r][c4+1] = v.y;
    tile[r][c4+2] = v.z; tile[r][c4+3] = v.w;
  }
  __syncthreads();
  #pragma unroll
  for (int i = 0; i < 2; ++i) {
    int idx = i * 256 + t;
    int c = idx >> 3, r8 = (idx & 7) * 8;
    bf16x8 pk;
    #pragma unroll
    for (int k = 0; k < 8; ++k) pk[k] = (bf16_t)tile[r8 + k][c];
    *(bf16x8*)(d + (size_t)(c0 + c) * R + r0 + r8) = pk;
  }
}

// ============================ tiny serial kernels ============================
__global__ void k_finalize(int* __restrict__ meta, float* __restrict__ aux_out) {
  if (threadIdx.x == 0 && blockIdx.x == 0) {
    int acc = 0;
    for (int e = 0; e < 8; ++e) { meta[24 + e] = acc; acc += meta[8 + e]; }
    const float* probsum = (const float*)(meta + 32);
    const float* zsum    = (const float*)(meta + 40);
    float s = 0.f;
    for (int e = 0; e < 8; ++e)
      s += ((float)meta[e] * (1.f / 8192.f)) * (probsum[e] * (1.f / 8192.f));
    aux_out[0] = 8.f * s * 0.01f + (zsum[0] * (1.f / 8192.f)) * 0.001f;
  }
}

__global__ __launch_bounds__(256) void k_assign(
    const int* __restrict__ eidx, float* __restrict__ gts,
    int* __restrict__ meta, int* __restrict__ list, float* __restrict__ gl,
    int* __restrict__ t2s)
{
  int t = blockIdx.x * 256 + threadIdx.x;
  int* cursor = meta + 16;
  const int* off = meta + 24;
  #pragma unroll
  for (int k = 0; k < 2; ++k) {
    int e = eidx[t*2 + k];
    float g = gts[t*2 + k];          // read before aliased write
    int pos = atomicAdd(&cursor[e], 1);
    int slot = off[e] + pos;
    list[slot] = t;
    gl[slot] = g;
    t2s[t*2 + k] = slot;
  }
}

// ====== grouped GEMM: 128x256 tile, BK=32, 8 waves (2Mx4N), per-wave 64x64 ======
// DEPTH-2 PREFETCH, 3 LDS buffers (m218 counted-vmcnt mechanism): stage tile t+2
// while computing t; VW(6) leaves tiles t+1,t+2 (6 loads) in flight -> ~1200cy
// stage->consume gap covers the ~900cy HBM latency that depth-1 (R4-R13) never did.
// LDS buf P @ P*24576 (72KB total; 2 blocks/CU): A[128][32] @0, B[256][32] @8192;
// line-pair swizzle (0 conflicts, R7); pre-swizzled global src + linear gload dest.
// Hazards: RAW = own VW(6)+BAR (vmcnt tracks gload_lds LDS-write completion, m135);
// WAR = buf[(t+2)%3] last read at tile t-1, whose closing BAR precedes this STG.
// Tail: VW(3) at NT-2, VW(0) at NT-1. Rotating offsets are scalars (no arrays).

#define BAR __builtin_amdgcn_s_barrier()
#define VW(N) asm volatile("s_waitcnt vmcnt(" #N ")" ::: "memory")

#define STG(T, OFF) do { \
  gload16(sA  + (size_t)(T) * 32, smem + (OFF) +         wv * 1024); \
  gload16(sB0 + (size_t)(T) * 32, smem + (OFF) +  8192 + wv * 1024); \
  gload16(sB1 + (size_t)(T) * 32, smem + (OFF) + 16384 + wv * 1024); } while (0)

#define COMP(OFF) do { \
  bf16x8 afr[4], bfr[4]; \
  _Pragma("unroll") for (int i_ = 0; i_ < 4; ++i_) \
    afr[i_] = *(const bf16x8*)(smem + (OFF) + a_off[i_]); \
  _Pragma("unroll") for (int j_ = 0; j_ < 4; ++j_) \
    bfr[j_] = *(const bf16x8*)(smem + (OFF) + 8192 + b_off[j_]); \
  __builtin_amdgcn_s_setprio(1); \
  _Pragma("unroll") for (int i_ = 0; i_ < 4; ++i_) \
    _Pragma("unroll") for (int j_ = 0; j_ < 4; ++j_) \
      acc[i_][j_] = mfma_bf16(afr[i_], bfr[j_], acc[i_][j_]); \
  __builtin_amdgcn_s_setprio(0); } while (0)

#define KLOOP3(NT) do { \
  STG(0, 0u); STG(1, 24576u); \
  unsigned cOff = 0u, nOff = 49152u; \
  for (int kt = 0; kt < (NT); ++kt) { \
    if (kt + 2 < (NT)) { STG(kt + 2, nOff); VW(6); } \
    else if (kt + 1 < (NT)) { VW(3); } \
    else { VW(0); } \
    BAR; COMP(cOff); BAR; \
    cOff = (cOff == 49152u) ? 0u : cOff + 24576u; \
    nOff = (nOff == 49152u) ? 0u : nOff + 24576u; \
  } \
} while (0)

// ============ GEMM1: H = gelu(Xn[list] @ W1t^T + b1), K=DM (NT=32) ============
__global__ __launch_bounds__(512, 4) void k_ffn1(
    const bf16_t* __restrict__ xn, const bf16_t* __restrict__ w1t,
    const float* __restrict__ b1, bf16_t* __restrict__ H,
    const int* __restrict__ list, const int* __restrict__ meta)
{
  __shared__ __align__(1024) char smem[73728];
  int e = blockIdx.z;
  int cnt = meta[8 + e];
  int m0 = blockIdx.y * 128;
  if (m0 >= cnt) return;
  int offe = meta[24 + e];
  int n0 = blockIdx.x * 256;

  int tid = threadIdx.x, lane = tid & 63, wv = tid >> 6;
  int wm = wv >> 2, wn = wv & 3;

  const bf16_t* sA; const bf16_t* sB0; const bf16_t* sB1;
  {
    int s = tid, line = s >> 3, u = s & 7, w = u ^ (line & 7);
    int row = (line << 1) | (w >> 2), ch = w & 3;
    int mrow = min(m0 + row, cnt - 1);
    int token = list[offe + mrow];
    sA = xn + (size_t)token * DM + ch * 8;
  }
  {
    int s = tid, line = s >> 3, u = s & 7, w = u ^ (line & 7);
    int row = (line << 1) | (w >> 2), ch = w & 3;
    sB0 = w1t + ((size_t)e * DF + n0 + row) * DM + ch * 8;
  }
  {
    int s = 512 + tid, line = s >> 3, u = s & 7, w = u ^ (line & 7);
    int row = (line << 1) | (w >> 2), ch = w & 3;
    sB1 = w1t + ((size_t)e * DF + n0 + row) * DM + ch * 8;
  }

  unsigned a_off[4], b_off[4];
  #pragma unroll
  for (int i = 0; i < 4; ++i) a_off[i] = swz_off(wm * 64 + i * 16 + (lane & 15), lane >> 4);
  #pragma unroll
  for (int j = 0; j < 4; ++j) b_off[j] = swz_off(wn * 64 + j * 16 + (lane & 15), lane >> 4);

  f32x4 acc[4][4];
  #pragma unroll
  for (int i = 0; i < 4; ++i)
    #pragma unroll
    for (int j = 0; j < 4; ++j)
      acc[i][j] = (f32x4){0.f, 0.f, 0.f, 0.f};

  KLOOP3(DM / 32);

  int rbase = wm * 64 + ((lane >> 4) << 2);
  int cbase = n0 + wn * 64 + (lane & 15);
  #pragma unroll
  for (int i = 0; i < 4; ++i) {
    #pragma unroll
    for (int q = 0; q < 4; ++q) {
      int mg = m0 + rbase + i * 16 + q;
      if (mg < cnt) {
        size_t hrow = (size_t)(offe + mg) * DF;
        #pragma unroll
        for (int j = 0; j < 4; ++j) {
          int col = cbase + j * 16;
          float hv = acc[i][j][q] + b1[e * DF + col];
          hv = 0.5f * hv * (1.f + erf_fast(hv * 0.70710678118f));
          H[hrow + col] = (bf16_t)hv;
        }
      }
    }
  }
}

// ============ GEMM2: Y[slot] = H[slot] @ W2t^T + b2 (bf16), K=DF (NT=128) ============
__global__ __launch_bounds__(512, 4) void k_ffn2(
    const bf16_t* __restrict__ H, const bf16_t* __restrict__ w2t,
    const float* __restrict__ b2, bf16_t* __restrict__ Y,
    const int* __restrict__ meta)
{
  __shared__ __align__(1024) char smem[73728];
  int e = blockIdx.z;
  int cnt = meta[8 + e];
  int m0 = blockIdx.y * 128;
  if (m0 >= cnt) return;
  int offe = meta[24 + e];
  int n0 = blockIdx.x * 256;

  int tid = threadIdx.x, lane = tid & 63, wv = tid >> 6;
  int wm = wv >> 2, wn = wv & 3;

  const bf16_t* sA; const bf16_t* sB0; const bf16_t* sB1;
  {
    int s = tid, line = s >> 3, u = s & 7, w = u ^ (line & 7);
    int row = (line << 1) | (w >> 2), ch = w & 3;
    int mrow = min(m0 + row, cnt - 1);
    sA = H + (size_t)(offe + mrow) * DF + ch * 8;
  }
  {
    int s = tid, line = s >> 3, u = s & 7, w = u ^ (line & 7);
    int row = (line << 1) | (w >> 2), ch = w & 3;
    sB0 = w2t + ((size_t)e * DM + n0 + row) * DF + ch * 8;
  }
  {
    int s = 512 + tid, line = s >> 3, u = s & 7, w = u ^ (line & 7);
    int row = (line << 1) | (w >> 2), ch = w & 3;
    sB1 = w2t + ((size_t)e * DM + n0 + row) * DF + ch * 8;
  }

  unsigned a_off[4], b_off[4];
  #pragma unroll
  for (int i = 0; i < 4; ++i) a_off[i] = swz_off(wm * 64 + i * 16 + (lane & 15), lane >> 4);
  #pragma unroll
  for (int j = 0; j < 4; ++j) b_off[j] = swz_off(wn * 64 + j * 16 + (lane & 15), lane >> 4);

  f32x4 acc[4][4];
  #pragma unroll
  for (int i = 0; i < 4; ++i)
    #pragma unroll
    for (int j = 0; j < 4; ++j)
      acc[i][j] = (f32x4){0.f, 0.f, 0.f, 0.f};

  KLOOP3(DF / 32);

  int rbase = wm * 64 + ((lane >> 4) << 2);
  int cbase = n0 + wn * 64 + (lane & 15);
  #pragma unroll
  for (int i = 0; i < 4; ++i) {
    #pragma unroll
    for (int q = 0; q < 4; ++q) {
      int mg = m0 + rbase + i * 16 + q;
      if (mg < cnt) {
        size_t yrow = (size_t)(offe + mg) * DM;
        #pragma unroll
        for (int j = 0; j < 4; ++j) {
          int col = cbase + j * 16;
          Y[yrow + col] = (bf16_t)(acc[i][j][q] + b2[e * DM + col]);
        }
      }
    }
  }
}

// ===== combine: out[t] += g0*Y[s0] + g1*Y[s1] (one wave per token, bf16 Y) =====
__global__ __launch_bounds__(256) void k_combine(
    const bf16_t* __restrict__ Y, const int* __restrict__ t2s,
    const float* __restrict__ gl, float* __restrict__ out)
{
  int lane = threadIdx.x & 63, wv = threadIdx.x >> 6;
  int t = blockIdx.x * 4 + wv;
  int s0 = t2s[t*2], s1 = t2s[t*2 + 1];
  float g0 = gl[s0], g1 = gl[s1];
  const bf16_t* y0 = Y + (size_t)s0 * DM;
  const bf16_t* y1 = Y + (size_t)s1 * DM;
  float* o = out + (size_t)t * DM;
  #pragma unroll
  for (int c = 0; c < 4; ++c) {
    int d = c * 256 + lane * 4;
    float4 r  = *(const float4*)(o + d);
    bf16x4 a = *(const bf16x4*)(y0 + d);
    bf16x4 b = *(const bf16x4*)(y1 + d);
    r.x += g0 * (float)a[0] + g1 * (float)b[0];
    r.y += g0 * (float)a[1] + g1 * (float)b[1];
    r.z += g0 * (float)a[2] + g1 * (float)b[2];
    r.w += g0 * (float)a[3] + g1 * (float)b[3];
    *(float4*)(o + d) = r;
  }
}

// ============================ launch ============================
extern "C" void kernel_launch(void* const* d_in, const int* in_sizes, int n_in,
                              void* d_out, int out_size, void* d_ws, size_t ws_size,
                              hipStream_t stream) {
  const float* x      = (const float*)d_in[0];
  const float* gate_w = (const float*)d_in[1];
  const float* ln_g   = (const float*)d_in[2];
  const float* ln_b   = (const float*)d_in[3];
  const float* w1     = (const float*)d_in[4];
  const float* b1     = (const float*)d_in[5];
  const float* w2     = (const float*)d_in[6];
  const float* b2     = (const float*)d_in[7];
  float* out = (float*)d_out;

  char* ws = (char*)d_ws;
  bf16_t* xn   = (bf16_t*)(ws);                                  // 16 MiB
  bf16_t* w1t  = (bf16_t*)(ws + 16777216ull);                    // 64 MiB [E][F][D]; dead after ffn1
  bf16_t* Y    = (bf16_t*)(ws + 16777216ull);                    //   reused: Y [NP][DM] bf16 (32 MiB)
  bf16_t* w2t  = (bf16_t*)(ws + 83886080ull);                    // 64 MiB [E][D][F]
  bf16_t* H    = (bf16_t*)(ws + 150994944ull);                   // 128 MiB [NP][F]
  int*    list = (int*)   (ws + 285212672ull);
  float*  gl   = (float*) (ws + 285278208ull);
  int*    eidx = (int*)   (ws + 285343744ull);
  float*  gts  = (float*) (ws + 285409280ull);                   // aliased as t2s after k_assign
  int*    t2s  = (int*)   (ws + 285409280ull);
  int*    meta = (int*)   (ws + 285474816ull);

  hipMemsetAsync(meta, 0, 256, stream);
  k_router<<<T_TOK / 4, 256, 0, stream>>>(x, gate_w, ln_g, ln_b, out, xn, eidx, gts, meta);
  k_convT2<<<16384, 256, 0, stream>>>(w1, w1t, w2, w2t);
  k_finalize<<<1, 1, 0, stream>>>(meta, out + (size_t)T_TOK * DM);
  k_assign<<<T_TOK / 256, 256, 0, stream>>>(eidx, gts, meta, list, gl, t2s);
  k_ffn1<<<dim3(DF / 256, 64, NE), 512, 0, stream>>>(xn, w1t, b1, H, list, meta);
  k_ffn2<<<dim3(DM / 256, 64, NE), 512, 0, stream>>>(H, w2t, b2, Y, meta);
  k_combine<<<T_TOK / 4, 256, 0, stream>>>(Y, t2s, gl, out);
}

// Round 15
// 632.867 us; speedup vs baseline: 1.0601x; 1.0180x over previous
//
#include <hip/hip_runtime.h>
#include <math.h>

typedef __bf16 bf16_t;
typedef bf16_t bf16x8 __attribute__((ext_vector_type(8)));
typedef bf16_t bf16x4 __attribute__((ext_vector_type(4)));
typedef float  f32x4  __attribute__((ext_vector_type(4)));

#define T_TOK 8192
#define DM 1024
#define DF 4096
#define NE 8
#define NP 16384  // total token-expert pairs = T_TOK * 2

__device__ __forceinline__ f32x4 mfma_bf16(bf16x8 a, bf16x8 b, f32x4 c) {
  return __builtin_amdgcn_mfma_f32_16x16x32_bf16(a, b, c, 0, 0, 0);
}

__device__ __forceinline__ void gload16(const void* g, void* l) {
  __builtin_amdgcn_global_load_lds((const __attribute__((address_space(1))) void*)g,
                                   (__attribute__((address_space(3))) void*)l, 16, 0, 0);
}

// Abramowitz-Stegun 7.1.26 erf, |err| <= 1.5e-7
__device__ __forceinline__ float erf_fast(float x) {
  float ax = fabsf(x);
  float t = 1.f / (1.f + 0.3275911f * ax);
  float p = t * (0.254829592f + t * (-0.284496736f + t * (1.421413741f +
            t * (-1.453152027f + t * 1.061405429f))));
  float r = 1.f - p * __expf(-ax * ax);
  return copysignf(r, x);
}

// Line-pair LDS swizzle within a [rows][32 k] bf16 subtile (64B rows).
// byte(row,ch) = (row>>1)*128 + ((((row&1)<<2)|ch) ^ ((row>>1)&7))*16  [R7: 0 conflicts]
__device__ __forceinline__ unsigned swz_off(int row, int ch) {
  return (unsigned)(((row >> 1) << 7) + (((((row & 1) << 2) | ch) ^ ((row >> 1) & 7)) << 4));
}

// meta layout (ints): [0..7]=cnt1 [8..15]=cnt2 [16..23]=cursor [24..31]=off
// [32..39]=probsum(float) [40]=zsum(float)

// ============================ router ============================
__global__ __launch_bounds__(256) void k_router(
    const float* __restrict__ x, const float* __restrict__ gate_w,
    const float* __restrict__ ln_g, const float* __restrict__ ln_b,
    float* __restrict__ out, bf16_t* __restrict__ xn,
    int* __restrict__ eidx, float* __restrict__ gts, int* __restrict__ meta)
{
  int* cnt1 = meta;
  int* cnt2 = meta + 8;
  float* probsum = (float*)(meta + 32);
  float* zsum    = (float*)(meta + 40);

  __shared__ float sprob[8];
  __shared__ float sz;
  __shared__ int sc1[8], sc2[8];
  if (threadIdx.x < 8) { sprob[threadIdx.x] = 0.f; sc1[threadIdx.x] = 0; sc2[threadIdx.x] = 0; }
  if (threadIdx.x == 8) sz = 0.f;
  __syncthreads();

  int lane = threadIdx.x & 63, wv = threadIdx.x >> 6;
  int t = blockIdx.x * 4 + wv;
  const float* xt = x + (size_t)t * DM;

  float4 v[4];
  float s1 = 0.f, s2 = 0.f;
  #pragma unroll
  for (int c = 0; c < 4; ++c) {
    v[c] = *(const float4*)(xt + c * 256 + lane * 4);
    s1 += v[c].x + v[c].y + v[c].z + v[c].w;
    s2 += v[c].x * v[c].x + v[c].y * v[c].y + v[c].z * v[c].z + v[c].w * v[c].w;
  }
  #pragma unroll
  for (int o = 32; o > 0; o >>= 1) { s1 += __shfl_xor(s1, o, 64); s2 += __shfl_xor(s2, o, 64); }
  float mu = s1 * (1.f / DM);
  float var = s2 * (1.f / DM) - mu * mu;
  float rstd = rsqrtf(var + 1e-5f);

  float xv[16];
  #pragma unroll
  for (int c = 0; c < 4; ++c) {
    int d = c * 256 + lane * 4;
    float4 g4 = *(const float4*)(ln_g + d);
    float4 b4 = *(const float4*)(ln_b + d);
    xv[c*4+0] = (v[c].x - mu) * rstd * g4.x + b4.x;
    xv[c*4+1] = (v[c].y - mu) * rstd * g4.y + b4.y;
    xv[c*4+2] = (v[c].z - mu) * rstd * g4.z + b4.z;
    xv[c*4+3] = (v[c].w - mu) * rstd * g4.w + b4.w;
    *(float4*)(out + (size_t)t * DM + d) = v[c];  // residual init
    bf16x4 pk = { (bf16_t)xv[c*4+0], (bf16_t)xv[c*4+1], (bf16_t)xv[c*4+2], (bf16_t)xv[c*4+3] };
    *(bf16x4*)(xn + (size_t)t * DM + d) = pk;
  }

  float lg[8];
  #pragma unroll
  for (int e = 0; e < 8; ++e) {
    float p = 0.f;
    #pragma unroll
    for (int c = 0; c < 4; ++c) {
      int d = c * 256 + lane * 4;
      float4 g4 = *(const float4*)(gate_w + e * DM + d);
      p += xv[c*4+0] * g4.x + xv[c*4+1] * g4.y + xv[c*4+2] * g4.z + xv[c*4+3] * g4.w;
    }
    #pragma unroll
    for (int o = 32; o > 0; o >>= 1) p += __shfl_xor(p, o, 64);
    lg[e] = p;
  }

  if (lane == 0) {
    float m = -1e30f;
    #pragma unroll
    for (int e = 0; e < 8; ++e) { lg[e] = fminf(fmaxf(lg[e], -10.f), 10.f); m = fmaxf(m, lg[e]); }
    float pr[8]; float se = 0.f;
    #pragma unroll
    for (int e = 0; e < 8; ++e) { pr[e] = expf(lg[e] - m); se += pr[e]; }
    float inv = 1.f / se;
    #pragma unroll
    for (int e = 0; e < 8; ++e) pr[e] *= inv;
    float lse = m + logf(se);

    int e0 = 0; float p0 = pr[0];
    #pragma unroll
    for (int e = 1; e < 8; ++e) if (pr[e] > p0) { p0 = pr[e]; e0 = e; }
    int e1 = -1; float p1 = -1.f;
    #pragma unroll
    for (int e = 0; e < 8; ++e) if (e != e0 && pr[e] > p1) { p1 = pr[e]; e1 = e; }
    float s = p0 + p1 + 1e-8f;
    eidx[t*2]   = e0; eidx[t*2+1] = e1;
    gts[t*2]    = p0 / s; gts[t*2+1] = p1 / s;

    atomicAdd(&sc1[e0], 1);
    atomicAdd(&sc2[e0], 1);
    atomicAdd(&sc2[e1], 1);
    #pragma unroll
    for (int e = 0; e < 8; ++e) atomicAdd(&sprob[e], pr[e]);
    atomicAdd(&sz, lse * lse);
  }
  __syncthreads();
  if (threadIdx.x < 8) {
    if (sc1[threadIdx.x]) atomicAdd(&cnt1[threadIdx.x], sc1[threadIdx.x]);
    if (sc2[threadIdx.x]) atomicAdd(&cnt2[threadIdx.x], sc2[threadIdx.x]);
    atomicAdd(&probsum[threadIdx.x], sprob[threadIdx.x]);
  }
  if (threadIdx.x == 8) atomicAdd(zsum, sz);
}

// ========== merged weight convert+transpose (w1 and w2 in one grid) ==========
__global__ __launch_bounds__(256) void k_convT2(
    const float* __restrict__ w1, bf16_t* __restrict__ w1t,
    const float* __restrict__ w2, bf16_t* __restrict__ w2t)
{
  int bid = blockIdx.x;
  const float* s; bf16_t* d; int R, C, c0, r0;
  if (bid < 8192) {
    int e = bid >> 10, rem = bid & 1023;
    R = DM; C = DF;
    s = w1 + (size_t)e * R * C; d = w1t + (size_t)e * R * C;
    c0 = (rem & 63) * 64; r0 = (rem >> 6) * 64;
  } else {
    int e = (bid - 8192) >> 10, rem = (bid - 8192) & 1023;
    R = DF; C = DM;
    s = w2 + (size_t)e * R * C; d = w2t + (size_t)e * R * C;
    c0 = (rem & 15) * 64; r0 = (rem >> 4) * 64;
  }

  __shared__ float tile[64][65];
  int t = threadIdx.x;
  #pragma unroll
  for (int i = 0; i < 4; ++i) {
    int idx = i * 256 + t;
    int r = idx >> 4, c4 = (idx & 15) * 4;
    float4 v = *(const float4*)(s + (size_t)(r0 + r) * C + c0 + c4);
    tile[r][c4]   = v.x; tile[r][c4+1] = v.y;
    tile[r][c4+2] = v.z; tile[r][c4+3] = v.w;
  }
  __syncthreads();
  #pragma unroll
  for (int i = 0; i < 2; ++i) {
    int idx = i * 256 + t;
    int c = idx >> 3, r8 = (idx & 7) * 8;
    bf16x8 pk;
    #pragma unroll
    for (int k = 0; k < 8; ++k) pk[k] = (bf16_t)tile[r8 + k][c];
    *(bf16x8*)(d + (size_t)(c0 + c) * R + r0 + r8) = pk;
  }
}

// ============================ tiny serial kernels ============================
__global__ void k_finalize(int* __restrict__ meta, float* __restrict__ aux_out) {
  if (threadIdx.x == 0 && blockIdx.x == 0) {
    int acc = 0;
    for (int e = 0; e < 8; ++e) { meta[24 + e] = acc; acc += meta[8 + e]; }
    const float* probsum = (const float*)(meta + 32);
    const float* zsum    = (const float*)(meta + 40);
    float s = 0.f;
    for (int e = 0; e < 8; ++e)
      s += ((float)meta[e] * (1.f / 8192.f)) * (probsum[e] * (1.f / 8192.f));
    aux_out[0] = 8.f * s * 0.01f + (zsum[0] * (1.f / 8192.f)) * 0.001f;
  }
}

__global__ __launch_bounds__(256) void k_assign(
    const int* __restrict__ eidx, float* __restrict__ gts,
    int* __restrict__ meta, int* __restrict__ list, float* __restrict__ gl,
    int* __restrict__ t2s)
{
  int t = blockIdx.x * 256 + threadIdx.x;
  int* cursor = meta + 16;
  const int* off = meta + 24;
  #pragma unroll
  for (int k = 0; k < 2; ++k) {
    int e = eidx[t*2 + k];
    float g = gts[t*2 + k];          // read before aliased write
    int pos = atomicAdd(&cursor[e], 1);
    int slot = off[e] + pos;
    list[slot] = t;
    gl[slot] = g;
    t2s[t*2 + k] = slot;
  }
}

// ====== grouped GEMM: 128x256 tile, BK=32, 8 waves (2Mx4N), per-wave 64x64 ======
// DEPTH-2 PREFETCH, 3 LDS buffers (R14, best) + SINGLE barrier per K-tile + x3
// unroll with literal buffer offsets.
// Per tile t: VW(3) [tile t landed; only t+1's 3 loads may stay in flight]; BAR
// [all waves see tile t]; STG(t+2) [issue early, flies under COMP]; COMP(t).
// WAR: STG(t+2) overwrites buf (t+2)%3, last read by COMP(t-1); every wave's
// ds_reads are lgkm-drained before its MFMAs (compiler), which precede the BAR
// all waves passed -> one barrier suffices. RAW: own VW(3) + BAR.
// Tail: tile NT-2 VW(3) no-stage; tile NT-1 VW(0). NT==2 (mod 3) for both GEMMs
// so the x3 main loop's last iteration stages exactly tiles NT-3..NT-1.
// LDS buf P @ P*24576 (72KB, 2 blocks/CU = 16 waves/CU): A[128][32] @0,
// B[256][32] @8192; line-pair swizzle (0 conflicts, R7); pre-swizzled global
// src + linear gload dest (rule #21 both-sides).

#define BAR __builtin_amdgcn_s_barrier()
#define VW(N) asm volatile("s_waitcnt vmcnt(" #N ")" ::: "memory")

#define STG(T, OFF) do { \
  gload16(sA  + (size_t)(T) * 32, smem + (OFF) +         wv * 1024); \
  gload16(sB0 + (size_t)(T) * 32, smem + (OFF) +  8192 + wv * 1024); \
  gload16(sB1 + (size_t)(T) * 32, smem + (OFF) + 16384 + wv * 1024); } while (0)

#define COMP(OFF) do { \
  bf16x8 afr[4], bfr[4]; \
  _Pragma("unroll") for (int i_ = 0; i_ < 4; ++i_) \
    afr[i_] = *(const bf16x8*)(smem + (OFF) + a_off[i_]); \
  _Pragma("unroll") for (int j_ = 0; j_ < 4; ++j_) \
    bfr[j_] = *(const bf16x8*)(smem + (OFF) + 8192 + b_off[j_]); \
  __builtin_amdgcn_s_setprio(1); \
  _Pragma("unroll") for (int i_ = 0; i_ < 4; ++i_) \
    _Pragma("unroll") for (int j_ = 0; j_ < 4; ++j_) \
      acc[i_][j_] = mfma_bf16(afr[i_], bfr[j_], acc[i_][j_]); \
  __builtin_amdgcn_s_setprio(0); } while (0)

#define KLOOP3U(NT) do { \
  STG(0, 0u); STG(1, 24576u); \
  for (int t_ = 0; t_ + 2 < (NT); t_ += 3) { \
    VW(3); BAR; STG(t_ + 2, 49152u); COMP(0u); \
    VW(3); BAR; STG(t_ + 3, 0u);     COMP(24576u); \
    VW(3); BAR; STG(t_ + 4, 24576u); COMP(49152u); \
  } \
  VW(3); BAR; COMP(0u); \
  VW(0); BAR; COMP(24576u); \
} while (0)

// ============ GEMM1: H = gelu(Xn[list] @ W1t^T + b1), K=DM (NT=32) ============
__global__ __launch_bounds__(512, 4) void k_ffn1(
    const bf16_t* __restrict__ xn, const bf16_t* __restrict__ w1t,
    const float* __restrict__ b1, bf16_t* __restrict__ H,
    const int* __restrict__ list, const int* __restrict__ meta)
{
  __shared__ __align__(1024) char smem[73728];
  int e = blockIdx.z;
  int cnt = meta[8 + e];
  int m0 = blockIdx.y * 128;
  if (m0 >= cnt) return;
  int offe = meta[24 + e];
  int n0 = blockIdx.x * 256;

  int tid = threadIdx.x, lane = tid & 63, wv = tid >> 6;
  int wm = wv >> 2, wn = wv & 3;

  const bf16_t* sA; const bf16_t* sB0; const bf16_t* sB1;
  {
    int s = tid, line = s >> 3, u = s & 7, w = u ^ (line & 7);
    int row = (line << 1) | (w >> 2), ch = w & 3;
    int mrow = min(m0 + row, cnt - 1);
    int token = list[offe + mrow];
    sA = xn + (size_t)token * DM + ch * 8;
  }
  {
    int s = tid, line = s >> 3, u = s & 7, w = u ^ (line & 7);
    int row = (line << 1) | (w >> 2), ch = w & 3;
    sB0 = w1t + ((size_t)e * DF + n0 + row) * DM + ch * 8;
  }
  {
    int s = 512 + tid, line = s >> 3, u = s & 7, w = u ^ (line & 7);
    int row = (line << 1) | (w >> 2), ch = w & 3;
    sB1 = w1t + ((size_t)e * DF + n0 + row) * DM + ch * 8;
  }

  unsigned a_off[4], b_off[4];
  #pragma unroll
  for (int i = 0; i < 4; ++i) a_off[i] = swz_off(wm * 64 + i * 16 + (lane & 15), lane >> 4);
  #pragma unroll
  for (int j = 0; j < 4; ++j) b_off[j] = swz_off(wn * 64 + j * 16 + (lane & 15), lane >> 4);

  f32x4 acc[4][4];
  #pragma unroll
  for (int i = 0; i < 4; ++i)
    #pragma unroll
    for (int j = 0; j < 4; ++j)
      acc[i][j] = (f32x4){0.f, 0.f, 0.f, 0.f};

  KLOOP3U(DM / 32);

  int rbase = wm * 64 + ((lane >> 4) << 2);
  int cbase = n0 + wn * 64 + (lane & 15);
  #pragma unroll
  for (int i = 0; i < 4; ++i) {
    #pragma unroll
    for (int q = 0; q < 4; ++q) {
      int mg = m0 + rbase + i * 16 + q;
      if (mg < cnt) {
        size_t hrow = (size_t)(offe + mg) * DF;
        #pragma unroll
        for (int j = 0; j < 4; ++j) {
          int col = cbase + j * 16;
          float hv = acc[i][j][q] + b1[e * DF + col];
          hv = 0.5f * hv * (1.f + erf_fast(hv * 0.70710678118f));
          H[hrow + col] = (bf16_t)hv;
        }
      }
    }
  }
}

// ============ GEMM2: Y[slot] = H[slot] @ W2t^T + b2 (bf16), K=DF (NT=128) ============
__global__ __launch_bounds__(512, 4) void k_ffn2(
    const bf16_t* __restrict__ H, const bf16_t* __restrict__ w2t,
    const float* __restrict__ b2, bf16_t* __restrict__ Y,
    const int* __restrict__ meta)
{
  __shared__ __align__(1024) char smem[73728];
  int e = blockIdx.z;
  int cnt = meta[8 + e];
  int m0 = blockIdx.y * 128;
  if (m0 >= cnt) return;
  int offe = meta[24 + e];
  int n0 = blockIdx.x * 256;

  int tid = threadIdx.x, lane = tid & 63, wv = tid >> 6;
  int wm = wv >> 2, wn = wv & 3;

  const bf16_t* sA; const bf16_t* sB0; const bf16_t* sB1;
  {
    int s = tid, line = s >> 3, u = s & 7, w = u ^ (line & 7);
    int row = (line << 1) | (w >> 2), ch = w & 3;
    int mrow = min(m0 + row, cnt - 1);
    sA = H + (size_t)(offe + mrow) * DF + ch * 8;
  }
  {
    int s = tid, line = s >> 3, u = s & 7, w = u ^ (line & 7);
    int row = (line << 1) | (w >> 2), ch = w & 3;
    sB0 = w2t + ((size_t)e * DM + n0 + row) * DF + ch * 8;
  }
  {
    int s = 512 + tid, line = s >> 3, u = s & 7, w = u ^ (line & 7);
    int row = (line << 1) | (w >> 2), ch = w & 3;
    sB1 = w2t + ((size_t)e * DM + n0 + row) * DF + ch * 8;
  }

  unsigned a_off[4], b_off[4];
  #pragma unroll
  for (int i = 0; i < 4; ++i) a_off[i] = swz_off(wm * 64 + i * 16 + (lane & 15), lane >> 4);
  #pragma unroll
  for (int j = 0; j < 4; ++j) b_off[j] = swz_off(wn * 64 + j * 16 + (lane & 15), lane >> 4);

  f32x4 acc[4][4];
  #pragma unroll
  for (int i = 0; i < 4; ++i)
    #pragma unroll
    for (int j = 0; j < 4; ++j)
      acc[i][j] = (f32x4){0.f, 0.f, 0.f, 0.f};

  KLOOP3U(DF / 32);

  int rbase = wm * 64 + ((lane >> 4) << 2);
  int cbase = n0 + wn * 64 + (lane & 15);
  #pragma unroll
  for (int i = 0; i < 4; ++i) {
    #pragma unroll
    for (int q = 0; q < 4; ++q) {
      int mg = m0 + rbase + i * 16 + q;
      if (mg < cnt) {
        size_t yrow = (size_t)(offe + mg) * DM;
        #pragma unroll
        for (int j = 0; j < 4; ++j) {
          int col = cbase + j * 16;
          Y[yrow + col] = (bf16_t)(acc[i][j][q] + b2[e * DM + col]);
        }
      }
    }
  }
}

// ===== combine: out[t] += g0*Y[s0] + g1*Y[s1] (one wave per token, bf16 Y) =====
__global__ __launch_bounds__(256) void k_combine(
    const bf16_t* __restrict__ Y, const int* __restrict__ t2s,
    const float* __restrict__ gl, float* __restrict__ out)
{
  int lane = threadIdx.x & 63, wv = threadIdx.x >> 6;
  int t = blockIdx.x * 4 + wv;
  int s0 = t2s[t*2], s1 = t2s[t*2 + 1];
  float g0 = gl[s0], g1 = gl[s1];
  const bf16_t* y0 = Y + (size_t)s0 * DM;
  const bf16_t* y1 = Y + (size_t)s1 * DM;
  float* o = out + (size_t)t * DM;
  #pragma unroll
  for (int c = 0; c < 4; ++c) {
    int d = c * 256 + lane * 4;
    float4 r  = *(const float4*)(o + d);
    bf16x4 a = *(const bf16x4*)(y0 + d);
    bf16x4 b = *(const bf16x4*)(y1 + d);
    r.x += g0 * (float)a[0] + g1 * (float)b[0];
    r.y += g0 * (float)a[1] + g1 * (float)b[1];
    r.z += g0 * (float)a[2] + g1 * (float)b[2];
    r.w += g0 * (float)a[3] + g1 * (float)b[3];
    *(float4*)(o + d) = r;
  }
}

// ============================ launch ============================
extern "C" void kernel_launch(void* const* d_in, const int* in_sizes, int n_in,
                              void* d_out, int out_size, void* d_ws, size_t ws_size,
                              hipStream_t stream) {
  const float* x      = (const float*)d_in[0];
  const float* gate_w = (const float*)d_in[1];
  const float* ln_g   = (const float*)d_in[2];
  const float* ln_b   = (const float*)d_in[3];
  const float* w1     = (const float*)d_in[4];
  const float* b1     = (const float*)d_in[5];
  const float* w2     = (const float*)d_in[6];
  const float* b2     = (const float*)d_in[7];
  float* out = (float*)d_out;

  char* ws = (char*)d_ws;
  bf16_t* xn   = (bf16_t*)(ws);                                  // 16 MiB
  bf16_t* w1t  = (bf16_t*)(ws + 16777216ull);                    // 64 MiB [E][F][D]; dead after ffn1
  bf16_t* Y    = (bf16_t*)(ws + 16777216ull);                    //   reused: Y [NP][DM] bf16 (32 MiB)
  bf16_t* w2t  = (bf16_t*)(ws + 83886080ull);                    // 64 MiB [E][D][F]
  bf16_t* H    = (bf16_t*)(ws + 150994944ull);                   // 128 MiB [NP][F]
  int*    list = (int*)   (ws + 285212672ull);
  float*  gl   = (float*) (ws + 285278208ull);
  int*    eidx = (int*)   (ws + 285343744ull);
  float*  gts  = (float*) (ws + 285409280ull);                   // aliased as t2s after k_assign
  int*    t2s  = (int*)   (ws + 285409280ull);
  int*    meta = (int*)   (ws + 285474816ull);

  hipMemsetAsync(meta, 0, 256, stream);
  k_router<<<T_TOK / 4, 256, 0, stream>>>(x, gate_w, ln_g, ln_b, out, xn, eidx, gts, meta);
  k_convT2<<<16384, 256, 0, stream>>>(w1, w1t, w2, w2t);
  k_finalize<<<1, 1, 0, stream>>>(meta, out + (size_t)T_TOK * DM);
  k_assign<<<T_TOK / 256, 256, 0, stream>>>(eidx, gts, meta, list, gl, t2s);
  k_ffn1<<<dim3(DF / 256, 64, NE), 512, 0, stream>>>(xn, w1t, b1, H, list, meta);
  k_ffn2<<<dim3(DM / 256, 64, NE), 512, 0, stream>>>(H, w2t, b2, Y, meta);
  k_combine<<<T_TOK / 4, 256, 0, stream>>>(Y, t2s, gl, out);
}